// Round 1
// baseline (228.845 us; speedup 1.0000x reference)
//
#include <hip/hip_runtime.h>

#define LSEQ 2048
#define DIN  1330
#define NB   8

__device__ __forceinline__ float lsef(float a, float b) {
  float m = fmaxf(a, b);
  float d = fminf(a, b) - m;          // <= 0
  return m + log1pf(__expf(d));
}

// ---------------- K1: h1[row][h] = x[row][:] @ w1[:][h] + b1[h] ----------------
// 256 thr = 32 rows x 8 h-quads. x loads float2 (rows 8B aligned), w1 float4.
__global__ __launch_bounds__(256) void k1_gemm(
    const float* __restrict__ x, const float* __restrict__ w1,
    const float* __restrict__ b1, float* __restrict__ h1) {
  const int tid = threadIdx.x;
  const int hq  = tid & 7;
  const int r   = tid >> 3;
  const int row = blockIdx.x * 32 + r;            // 0..16383
  const float* xp = x + (long)row * DIN;
  const float* wp = w1 + hq * 4;
  float ax = 0.f, ay = 0.f, az = 0.f, aw = 0.f;
  int d = 0;
  #pragma unroll 4
  for (; d < 1328; d += 4) {
    float2 x01 = *(const float2*)(xp + d);
    float2 x23 = *(const float2*)(xp + d + 2);
    float4 w0 = *(const float4*)(wp + (d + 0) * 32);
    float4 w1v = *(const float4*)(wp + (d + 1) * 32);
    float4 w2v = *(const float4*)(wp + (d + 2) * 32);
    float4 w3v = *(const float4*)(wp + (d + 3) * 32);
    ax += x01.x * w0.x + x01.y * w1v.x + x23.x * w2v.x + x23.y * w3v.x;
    ay += x01.x * w0.y + x01.y * w1v.y + x23.x * w2v.y + x23.y * w3v.y;
    az += x01.x * w0.z + x01.y * w1v.z + x23.x * w2v.z + x23.y * w3v.z;
    aw += x01.x * w0.w + x01.y * w1v.w + x23.x * w2v.w + x23.y * w3v.w;
  }
  // remainder d = 1328, 1329
  {
    float xr0 = xp[1328], xr1 = xp[1329];
    float4 wr0 = *(const float4*)(wp + 1328 * 32);
    float4 wr1 = *(const float4*)(wp + 1329 * 32);
    ax += xr0 * wr0.x + xr1 * wr1.x;
    ay += xr0 * wr0.y + xr1 * wr1.y;
    az += xr0 * wr0.z + xr1 * wr1.z;
    aw += xr0 * wr0.w + xr1 * wr1.w;
  }
  float4 bv = *(const float4*)(b1 + hq * 4);
  ax += bv.x; ay += bv.y; az += bv.z; aw += bv.w;
  float4 o; o.x = ax; o.y = ay; o.z = az; o.w = aw;
  *(float4*)(h1 + (long)row * 32 + hq * 4) = o;
}

// ---------------- K2: em = relu(conv1d(h1)+cb) @ w2 + b2 ----------------
__global__ __launch_bounds__(256) void k2_conv(
    const float* __restrict__ h1, const float* __restrict__ cw,
    const float* __restrict__ cb, const float* __restrict__ w2,
    const float* __restrict__ b2, float* __restrict__ em) {
  const int gid = blockIdx.x * 256 + threadIdx.x;   // 0..16383
  const int li  = gid & (LSEQ - 1);
  const float* h0 = h1 + (long)gid * 32;
  const bool hasm = (li > 0), hasp = (li < LSEQ - 1);
  float s[16];
  #pragma unroll
  for (int o = 0; o < 16; ++o) s[o] = cb[o];
  for (int i = 0; i < 32; ++i) {
    float a = hasm ? h0[i - 32] : 0.f;
    float c = h0[i];
    float dd = hasp ? h0[i + 32] : 0.f;
    #pragma unroll
    for (int o = 0; o < 16; ++o) {
      const float* w = cw + o * 96 + i * 3;
      s[o] += a * w[0] + c * w[1] + dd * w[2];
    }
  }
  float e0 = b2[0], e1 = b2[1];
  #pragma unroll
  for (int o = 0; o < 16; ++o) {
    float rr = fmaxf(s[o], 0.f);
    e0 += rr * w2[o * 2];
    e1 += rr * w2[o * 2 + 1];
  }
  float2 ev; ev.x = e0; ev.y = e1;
  *(float2*)(em + (long)gid * 2) = ev;
}

// ---------------- K3: per-batch CRF (score, log-partition, Viterbi) ----------------
__global__ __launch_bounds__(256) void k3_crf(
    const float* __restrict__ em, const int* __restrict__ tokens_length,
    const int* __restrict__ labels, const float* __restrict__ start_trans,
    const float* __restrict__ end_trans, const float* __restrict__ trans,
    float* __restrict__ llh, float* __restrict__ out) {
  __shared__ float sem[LSEQ * 2];
  __shared__ unsigned char hist[LSEQ];
  __shared__ float4 mats[256];
  __shared__ float red[256];
  __shared__ unsigned char bmA[256], bmB[256];
  __shared__ int s_last;

  const int t = threadIdx.x;
  const int b = blockIdx.x;
  const int len = tokens_length[b];
  const float t00 = trans[0], t01 = trans[1], t10 = trans[2], t11 = trans[3];
  const float st0 = start_trans[0], st1 = start_trans[1];
  const float en0 = end_trans[0], en1 = end_trans[1];
  const int* lab = labels + b * LSEQ;

  // stage em[b] -> LDS; hist := identity map (h0=0,h1=1 -> byte 2)
  {
    const float4* src4 = (const float4*)(em + (long)b * LSEQ * 2);
    float4* dst4 = (float4*)sem;
    #pragma unroll
    for (int i = t; i < LSEQ * 2 / 4; i += 256) dst4[i] = src4[i];
    #pragma unroll
    for (int l = t; l < LSEQ; l += 256) hist[l] = 2;
  }
  __syncthreads();

  // ---- gold-score partial (parallel) ----
  float sc = 0.f;
  {
    const int base = t * 8;
    #pragma unroll
    for (int k = 0; k < 8; ++k) {
      int l = base + k;
      if (l >= 1 && l < len) {
        int lp = lab[l - 1], lc = lab[l];
        sc += trans[lp * 2 + lc] + sem[2 * l + lc];
      }
    }
  }
  red[t] = sc;

  // ---- log-partition chunk product (log-semiring 2x2) ----
  float p00 = 0.f, p01 = -1e30f, p10 = -1e30f, p11 = 0.f;
  {
    int lo = t * 8; if (lo < 1) lo = 1;
    int hi = t * 8 + 8; if (hi > len) hi = len;
    for (int l = lo; l < hi; ++l) {
      float e0 = sem[2 * l], e1 = sem[2 * l + 1];
      float n00 = lsef(p00 + t00, p01 + t10) + e0;
      float n01 = lsef(p00 + t01, p01 + t11) + e1;
      float n10 = lsef(p10 + t00, p11 + t10) + e0;
      float n11 = lsef(p10 + t01, p11 + t11) + e1;
      p00 = n00; p01 = n01; p10 = n10; p11 = n11;
    }
  }
  { float4 m; m.x = p00; m.y = p01; m.z = p10; m.w = p11; mats[t] = m; }
  __syncthreads();

  // score tree-sum (reads [n,2n), writes [0,n) - disjoint)
  for (int n = 128; n >= 1; n >>= 1) {
    if (t < n) red[t] += red[t + n];
    __syncthreads();
  }
  // ordered non-commutative matrix tree-reduce
  for (int n = 128; n >= 1; n >>= 1) {
    float4 A, B; const bool act = (t < n);
    if (act) { A = mats[2 * t]; B = mats[2 * t + 1]; }
    __syncthreads();
    if (act) {
      float4 C;
      C.x = lsef(A.x + B.x, A.y + B.z);
      C.y = lsef(A.x + B.y, A.y + B.w);
      C.z = lsef(A.z + B.x, A.w + B.z);
      C.w = lsef(A.z + B.y, A.w + B.w);
      mats[t] = C;
    }
    __syncthreads();
  }

  if (t == 0) {
    int lab0 = lab[0];
    float s0 = (lab0 ? st1 : st0) + sem[lab0];
    int labe = lab[len - 1];
    float score = red[0] + s0 + (labe ? en1 : en0);
    float4 M = mats[0];
    float a00 = st0 + sem[0], a01 = st1 + sem[1];
    float af0 = lsef(a00 + M.x, a01 + M.z);
    float af1 = lsef(a00 + M.y, a01 + M.w);
    float norm = lsef(af0 + en0, af1 + en1);
    llh[b] = score - norm;
  }

  // ---- sequential Viterbi forward (bit-exact ref order) ----
  if (t == 0) {
    float v0 = st0 + sem[0], v1 = st1 + sem[1];
    for (int l = 1; l < len; ++l) {
      float e0 = sem[2 * l], e1 = sem[2 * l + 1];
      float s00 = v0 + t00, s10 = v1 + t10;
      float s01 = v0 + t01, s11 = v1 + t11;
      unsigned char h =
          (unsigned char)((s00 >= s10 ? 0 : 1) | ((s01 >= s11 ? 0 : 1) << 1));
      v0 = fmaxf(s00, s10) + e0;
      v1 = fmaxf(s01, s11) + e1;
      hist[l] = h;
    }
    s_last = (v0 + en0 >= v1 + en1) ? 0 : 1;
  }
  __syncthreads();
  const int last = s_last;

  // ---- backtrace: exact parallel map-composition suffix scan ----
  {
    int lo = (t == 0) ? 1 : t * 8;
    int hi = t * 8 + 8;
    int m0 = 0, m1 = 1;
    for (int l = hi - 1; l >= lo; --l) {
      int h = hist[l];
      m0 = (h >> m0) & 1;
      m1 = (h >> m1) & 1;
    }
    bmA[t] = (unsigned char)(m0 | (m1 << 1));
  }
  __syncthreads();
  {
    unsigned char* sarr = bmA; unsigned char* darr = bmB;
    for (int off = 1; off < 256; off <<= 1) {
      int a = sarr[t];
      int c = a;
      if (t + off < 256) {
        int bm = sarr[t + off];
        int c0 = (a >> (bm & 1)) & 1;
        int c1 = (a >> ((bm >> 1) & 1)) & 1;
        c = c0 | (c1 << 1);
      }
      darr[t] = (unsigned char)c;
      __syncthreads();
      unsigned char* tmp = sarr; sarr = darr; darr = tmp;
    }
    // sarr[t] = S_t = T_t o T_{t+1} o ... o T_255
    int x = (t == 255) ? last : ((sarr[t + 1] >> last) & 1);
    int lo = (t == 0) ? 1 : t * 8;
    int hi = t * 8 + 8;
    float* tout = out + 1 + b * LSEQ;
    for (int l = hi - 1; l >= lo; --l) {
      x = (hist[l] >> x) & 1;
      int p = l - 1;
      tout[p] = (p < len) ? (float)x : 0.0f;
    }
    if (t == 255) tout[LSEQ - 1] = ((LSEQ - 1) < len) ? (float)last : 0.0f;
  }
}

// ---------------- K4: deterministic final sum ----------------
__global__ void k4_final(const float* __restrict__ llh, float* __restrict__ out) {
  if (threadIdx.x == 0 && blockIdx.x == 0) {
    float s = 0.f;
    #pragma unroll
    for (int i = 0; i < NB; ++i) s += llh[i];
    out[0] = -s;
  }
}

extern "C" void kernel_launch(void* const* d_in, const int* in_sizes, int n_in,
                              void* d_out, int out_size, void* d_ws, size_t ws_size,
                              hipStream_t stream) {
  const float* x  = (const float*)d_in[0];
  const int*   tl = (const int*)d_in[1];
  const int*   lb = (const int*)d_in[2];
  const float* w1 = (const float*)d_in[3];
  const float* b1 = (const float*)d_in[4];
  const float* cw = (const float*)d_in[5];
  const float* cb = (const float*)d_in[6];
  const float* w2 = (const float*)d_in[7];
  const float* b2 = (const float*)d_in[8];
  const float* st = (const float*)d_in[9];
  const float* en = (const float*)d_in[10];
  const float* tr = (const float*)d_in[11];
  float* out = (float*)d_out;
  float* ws  = (float*)d_ws;

  float* h1  = ws;                       // 16384*32 = 524288 floats
  float* em  = ws + 16384 * 32;          // 16384*2  =  32768 floats
  float* llh = em + 16384 * 2;           // 8 floats

  hipLaunchKernelGGL(k1_gemm, dim3(512), dim3(256), 0, stream, x, w1, b1, h1);
  hipLaunchKernelGGL(k2_conv, dim3(64), dim3(256), 0, stream, h1, cw, cb, w2, b2, em);
  hipLaunchKernelGGL(k3_crf, dim3(NB), dim3(256), 0, stream, em, tl, lb, st, en, tr, llh, out);
  hipLaunchKernelGGL(k4_final, dim3(1), dim3(64), 0, stream, llh, out);
}

// Round 2
// 186.821 us; speedup vs baseline: 1.2249x; 1.2249x over previous
//
#include <hip/hip_runtime.h>

#define LSEQ 2048
#define DIN  1330
#define NB   8
#define SPLITK 8
#define KCH 167          // ceil(1330/8) -> chunks [s*167, min(1330,(s+1)*167))
#define SK  16           // k-subtile
#define NSUB 12          // 12*16 = 192 >= 167 (zero-padded)
#define TR  128          // rows per block

__device__ __forceinline__ float lsef(float a, float b) {
  float m = fmaxf(a, b);
  float d = fminf(a, b) - m;
  return m + log1pf(__expf(d));
}

// ---------------- K1: split-k partial GEMM  p[s] = x[:,ks]@w1[ks,:] ----------------
// block 128 thr: hg=tid&3 (8 h), rg=tid>>2 (4 rows). TR=128 rows/block.
__global__ __launch_bounds__(128, 2) void k1_gemm(
    const float* __restrict__ x, const float* __restrict__ w1,
    float* __restrict__ p) {
  __shared__ float xs[2][SK][132];

  const int tid = threadIdx.x;
  const int rb  = blockIdx.x >> 3;
  const int s   = blockIdx.x & 7;
  const int k0  = s * KCH;
  const int kend = (k0 + KCH < DIN) ? (k0 + KCH) : DIN;

  const int hg = tid & 3;
  const int h0 = hg << 3;
  const int rg = tid >> 2;             // 0..31
  const long row0 = (long)rb * TR;

  float acc[4][8];
  #pragma unroll
  for (int i = 0; i < 4; ++i)
    #pragma unroll
    for (int j = 0; j < 8; ++j) acc[i][j] = 0.f;

  const float* wbase = w1 + h0;
  const float* xsrd = &xs[0][0][0] + rg * 4;   // + bufi*SK*132 + kk*132

  float2 stv[8];

  // stage_load for subtile t: k-range [k0 + t*SK, +SK)
  auto stage_load = [&](int t) {
    const int kbase = k0 + t * SK;
    #pragma unroll
    for (int j = 0; j < 8; ++j) {
      const int idx = j * 128 + tid;
      const int kp  = idx & 7;          // 8 kpairs
      const int row = idx >> 3;         // 0..127
      const int kg  = kbase + kp * 2;
      float2 v; v.x = 0.f; v.y = 0.f;
      if (kg < kend) {
        const float* xp = x + (row0 + row) * DIN + kg;
        if (kg + 1 < kend) v = *(const float2*)xp;
        else v.x = *xp;
      }
      stv[j] = v;
    }
  };
  auto stage_write = [&](int bi) {
    #pragma unroll
    for (int j = 0; j < 8; ++j) {
      const int idx = j * 128 + tid;
      const int kp  = idx & 7;
      const int row = idx >> 3;
      xs[bi][kp * 2][row]     = stv[j].x;
      xs[bi][kp * 2 + 1][row] = stv[j].y;
    }
  };

  stage_load(0);
  stage_write(0);
  __syncthreads();

  for (int t = 0; t < NSUB; ++t) {
    const int bi = t & 1;
    if (t + 1 < NSUB) stage_load(t + 1);

    const int kbase = k0 + t * SK;
    const float* xr = xsrd + bi * (SK * 132);
    #pragma unroll 4
    for (int kk = 0; kk < SK; ++kk) {
      int kw = kbase + kk; kw = (kw < DIN) ? kw : (DIN - 1);
      const float4 x4 = *(const float4*)(xr + kk * 132);
      const float4 wv0 = *(const float4*)(wbase + kw * 32);
      const float4 wv1 = *(const float4*)(wbase + kw * 32 + 4);
      const float xv[4] = {x4.x, x4.y, x4.z, x4.w};
      const float wv[8] = {wv0.x, wv0.y, wv0.z, wv0.w, wv1.x, wv1.y, wv1.z, wv1.w};
      #pragma unroll
      for (int i = 0; i < 4; ++i)
        #pragma unroll
        for (int j = 0; j < 8; ++j)
          acc[i][j] += xv[i] * wv[j];
    }

    if (t + 1 < NSUB) stage_write((t + 1) & 1);
    __syncthreads();
  }

  // write partial tile
  float* ps = p + (long)s * (16384 * 32);
  #pragma unroll
  for (int i = 0; i < 4; ++i) {
    const long row = row0 + rg * 4 + i;
    float4 a; a.x = acc[i][0]; a.y = acc[i][1]; a.z = acc[i][2]; a.w = acc[i][3];
    float4 b; b.x = acc[i][4]; b.y = acc[i][5]; b.z = acc[i][6]; b.w = acc[i][7];
    *(float4*)(ps + row * 32 + h0)     = a;
    *(float4*)(ps + row * 32 + h0 + 4) = b;
  }
}

// ---------------- K1b: h1 = sum_s p[s] + b1  (in-place into p[0]) ----------------
__global__ __launch_bounds__(256) void k1b_reduce(
    float* __restrict__ p, const float* __restrict__ b1) {
  const int gid = blockIdx.x * 256 + threadIdx.x;   // 0..131071 float4s
  float4* p4 = (float4*)p;
  float4 a = p4[gid];
  #pragma unroll
  for (int s = 1; s < SPLITK; ++s) {
    float4 v = p4[(long)s * 131072 + gid];
    a.x += v.x; a.y += v.y; a.z += v.z; a.w += v.w;
  }
  float4 bv = ((const float4*)b1)[gid & 7];
  a.x += bv.x; a.y += bv.y; a.z += bv.z; a.w += bv.w;
  p4[gid] = a;
}

// ---------------- K2: em = relu(conv1d(h1)+cb) @ w2 + b2 ----------------
// 8 threads per row, each handles 4 input channels; shfl-reduce before relu.
__global__ __launch_bounds__(256) void k2_conv(
    const float* __restrict__ h1, const float* __restrict__ cw,
    const float* __restrict__ cb, const float* __restrict__ w2,
    const float* __restrict__ b2, float* __restrict__ em) {
  const int g = blockIdx.x * 256 + threadIdx.x;   // 0..131071
  const int row  = g >> 3;
  const int isub = g & 7;
  const int i0   = isub << 2;
  const int li   = row & (LSEQ - 1);

  const float* hb = h1 + (long)row * 32 + i0;
  float4 z; z.x = z.y = z.z = z.w = 0.f;
  float4 hm = (li > 0)        ? *(const float4*)(hb - 32) : z;
  float4 hc = *(const float4*)hb;
  float4 hp = (li < LSEQ - 1) ? *(const float4*)(hb + 32) : z;

  float s[16];
  #pragma unroll
  for (int o = 0; o < 16; ++o) {
    const float4* wp = (const float4*)(cw + o * 96 + i0 * 3);
    const float4 wa = wp[0], wb = wp[1], wc = wp[2];
    s[o] = hm.x * wa.x + hc.x * wa.y + hp.x * wa.z
         + hm.y * wa.w + hc.y * wb.x + hp.y * wb.y
         + hm.z * wb.z + hc.z * wb.w + hp.z * wc.x
         + hm.w * wc.y + hc.w * wc.z + hp.w * wc.w;
  }
  #pragma unroll
  for (int o = 0; o < 16; ++o) {
    s[o] += __shfl_xor(s[o], 1, 8);
    s[o] += __shfl_xor(s[o], 2, 8);
    s[o] += __shfl_xor(s[o], 4, 8);
  }
  if (isub == 0) {
    float e0 = b2[0], e1 = b2[1];
    #pragma unroll
    for (int o = 0; o < 16; ++o) {
      float rr = fmaxf(s[o] + cb[o], 0.f);
      e0 += rr * w2[o * 2];
      e1 += rr * w2[o * 2 + 1];
    }
    float2 ev; ev.x = e0; ev.y = e1;
    *(float2*)(em + (long)row * 2) = ev;
  }
}

// ---------------- K3: per-batch CRF (score, log-partition, Viterbi) ----------------
__global__ __launch_bounds__(256) void k3_crf(
    const float* __restrict__ em, const int* __restrict__ tokens_length,
    const int* __restrict__ labels, const float* __restrict__ start_trans,
    const float* __restrict__ end_trans, const float* __restrict__ trans,
    float* __restrict__ llh, float* __restrict__ out) {
  __shared__ float sem[LSEQ * 2];
  __shared__ unsigned char hist[LSEQ];
  __shared__ float4 mats[256];
  __shared__ float red[256];
  __shared__ unsigned char bmA[256], bmB[256];
  __shared__ int s_last;

  const int t = threadIdx.x;
  const int b = blockIdx.x;
  const int len = tokens_length[b];
  const float t00 = trans[0], t01 = trans[1], t10 = trans[2], t11 = trans[3];
  const float st0 = start_trans[0], st1 = start_trans[1];
  const float en0 = end_trans[0], en1 = end_trans[1];
  const int* lab = labels + b * LSEQ;

  {
    const float4* src4 = (const float4*)(em + (long)b * LSEQ * 2);
    float4* dst4 = (float4*)sem;
    #pragma unroll
    for (int i = t; i < LSEQ * 2 / 4; i += 256) dst4[i] = src4[i];
    #pragma unroll
    for (int l = t; l < LSEQ; l += 256) hist[l] = 2;
  }
  __syncthreads();

  // gold-score partial
  float sc = 0.f;
  {
    const int base = t * 8;
    #pragma unroll
    for (int k = 0; k < 8; ++k) {
      int l = base + k;
      if (l >= 1 && l < len) {
        int lp = lab[l - 1], lc = lab[l];
        sc += trans[lp * 2 + lc] + sem[2 * l + lc];
      }
    }
  }
  red[t] = sc;

  // log-partition chunk product
  float p00 = 0.f, p01 = -1e30f, p10 = -1e30f, p11 = 0.f;
  {
    int lo = t * 8; if (lo < 1) lo = 1;
    int hi = t * 8 + 8; if (hi > len) hi = len;
    for (int l = lo; l < hi; ++l) {
      float e0 = sem[2 * l], e1 = sem[2 * l + 1];
      float n00 = lsef(p00 + t00, p01 + t10) + e0;
      float n01 = lsef(p00 + t01, p01 + t11) + e1;
      float n10 = lsef(p10 + t00, p11 + t10) + e0;
      float n11 = lsef(p10 + t01, p11 + t11) + e1;
      p00 = n00; p01 = n01; p10 = n10; p11 = n11;
    }
  }
  { float4 m; m.x = p00; m.y = p01; m.z = p10; m.w = p11; mats[t] = m; }
  __syncthreads();

  for (int n = 128; n >= 1; n >>= 1) {
    if (t < n) red[t] += red[t + n];
    __syncthreads();
  }
  for (int n = 128; n >= 1; n >>= 1) {
    float4 A, B; const bool act = (t < n);
    if (act) { A = mats[2 * t]; B = mats[2 * t + 1]; }
    __syncthreads();
    if (act) {
      float4 C;
      C.x = lsef(A.x + B.x, A.y + B.z);
      C.y = lsef(A.x + B.y, A.y + B.w);
      C.z = lsef(A.z + B.x, A.w + B.z);
      C.w = lsef(A.z + B.y, A.w + B.w);
      mats[t] = C;
    }
    __syncthreads();
  }

  if (t == 0) {
    int lab0 = lab[0];
    float s0 = (lab0 ? st1 : st0) + sem[lab0];
    int labe = lab[len - 1];
    float score = red[0] + s0 + (labe ? en1 : en0);
    float4 M = mats[0];
    float a00 = st0 + sem[0], a01 = st1 + sem[1];
    float af0 = lsef(a00 + M.x, a01 + M.z);
    float af1 = lsef(a00 + M.y, a01 + M.w);
    float norm = lsef(af0 + en0, af1 + en1);
    llh[b] = score - norm;
  }

  // sequential Viterbi forward (bit-exact ref order)
  if (t == 0) {
    float v0 = st0 + sem[0], v1 = st1 + sem[1];
    for (int l = 1; l < len; ++l) {
      float e0 = sem[2 * l], e1 = sem[2 * l + 1];
      float s00 = v0 + t00, s10 = v1 + t10;
      float s01 = v0 + t01, s11 = v1 + t11;
      unsigned char h =
          (unsigned char)((s00 >= s10 ? 0 : 1) | ((s01 >= s11 ? 0 : 1) << 1));
      v0 = fmaxf(s00, s10) + e0;
      v1 = fmaxf(s01, s11) + e1;
      hist[l] = h;
    }
    s_last = (v0 + en0 >= v1 + en1) ? 0 : 1;
  }
  __syncthreads();
  const int last = s_last;

  // backtrace: parallel map-composition suffix scan (exact)
  {
    int lo = (t == 0) ? 1 : t * 8;
    int hi = t * 8 + 8;
    int m0 = 0, m1 = 1;
    for (int l = hi - 1; l >= lo; --l) {
      int h = hist[l];
      m0 = (h >> m0) & 1;
      m1 = (h >> m1) & 1;
    }
    bmA[t] = (unsigned char)(m0 | (m1 << 1));
  }
  __syncthreads();
  {
    unsigned char* sarr = bmA; unsigned char* darr = bmB;
    for (int off = 1; off < 256; off <<= 1) {
      int a = sarr[t];
      int c = a;
      if (t + off < 256) {
        int bm = sarr[t + off];
        int c0 = (a >> (bm & 1)) & 1;
        int c1 = (a >> ((bm >> 1) & 1)) & 1;
        c = c0 | (c1 << 1);
      }
      darr[t] = (unsigned char)c;
      __syncthreads();
      unsigned char* tmp = sarr; sarr = darr; darr = tmp;
    }
    int xv = (t == 255) ? last : ((sarr[t + 1] >> last) & 1);
    int lo = (t == 0) ? 1 : t * 8;
    int hi = t * 8 + 8;
    float* tout = out + 1 + b * LSEQ;
    for (int l = hi - 1; l >= lo; --l) {
      xv = (hist[l] >> xv) & 1;
      int pidx = l - 1;
      tout[pidx] = (pidx < len) ? (float)xv : 0.0f;
    }
    if (t == 255) tout[LSEQ - 1] = ((LSEQ - 1) < len) ? (float)last : 0.0f;
  }
}

// ---------------- K4: deterministic final sum ----------------
__global__ void k4_final(const float* __restrict__ llh, float* __restrict__ out) {
  if (threadIdx.x == 0 && blockIdx.x == 0) {
    float s = 0.f;
    #pragma unroll
    for (int i = 0; i < NB; ++i) s += llh[i];
    out[0] = -s;
  }
}

extern "C" void kernel_launch(void* const* d_in, const int* in_sizes, int n_in,
                              void* d_out, int out_size, void* d_ws, size_t ws_size,
                              hipStream_t stream) {
  const float* x  = (const float*)d_in[0];
  const int*   tl = (const int*)d_in[1];
  const int*   lb = (const int*)d_in[2];
  const float* w1 = (const float*)d_in[3];
  const float* b1 = (const float*)d_in[4];
  const float* cw = (const float*)d_in[5];
  const float* cb = (const float*)d_in[6];
  const float* w2 = (const float*)d_in[7];
  const float* b2 = (const float*)d_in[8];
  const float* st = (const float*)d_in[9];
  const float* en = (const float*)d_in[10];
  const float* tr = (const float*)d_in[11];
  float* out = (float*)d_out;
  float* ws  = (float*)d_ws;

  float* p   = ws;                                 // 8 * 524288 floats (16 MB); h1 = p[0] after reduce
  float* em  = ws + (long)SPLITK * 524288;         // 32768 floats
  float* llh = em + 32768;                         // 8 floats

  hipLaunchKernelGGL(k1_gemm, dim3(128 * SPLITK), dim3(128), 0, stream, x, w1, p);
  hipLaunchKernelGGL(k1b_reduce, dim3(512), dim3(256), 0, stream, p, b1);
  hipLaunchKernelGGL(k2_conv, dim3(512), dim3(256), 0, stream, p, cw, cb, w2, b2, em);
  hipLaunchKernelGGL(k3_crf, dim3(NB), dim3(256), 0, stream, em, tl, lb, st, en, tr, llh, out);
  hipLaunchKernelGGL(k4_final, dim3(1), dim3(64), 0, stream, llh, out);
}

// Round 3
// 168.759 us; speedup vs baseline: 1.3560x; 1.1070x over previous
//
#include <hip/hip_runtime.h>

#define LSEQ 2048
#define DIN  1330
#define NB   8
#define SPLITK 8
#define KCH 167          // ceil(1330/8)
#define SK  16           // k-subtile
#define NSUB 12          // 12*16 = 192 >= 167 (zero-padded)
#define TR  128          // rows per block
#define VGRP 16          // viterbi unroll group

__device__ __forceinline__ float lsef(float a, float b) {
  float m = fmaxf(a, b);
  float d = fminf(a, b) - m;
  return m + log1pf(__expf(d));
}

// ---------------- K1: split-k partial GEMM  p[s] = x[:,ks]@w1[ks,:] ----------------
__global__ __launch_bounds__(128, 2) void k1_gemm(
    const float* __restrict__ x, const float* __restrict__ w1,
    float* __restrict__ p) {
  __shared__ float xs[2][SK][132];

  const int tid = threadIdx.x;
  const int rb  = blockIdx.x >> 3;
  const int s   = blockIdx.x & 7;
  const int k0  = s * KCH;
  const int kend = (k0 + KCH < DIN) ? (k0 + KCH) : DIN;

  const int hg = tid & 3;
  const int h0 = hg << 3;
  const int rg = tid >> 2;             // 0..31
  const long row0 = (long)rb * TR;

  float acc[4][8];
  #pragma unroll
  for (int i = 0; i < 4; ++i)
    #pragma unroll
    for (int j = 0; j < 8; ++j) acc[i][j] = 0.f;

  const float* wbase = w1 + h0;
  const float* xsrd = &xs[0][0][0] + rg * 4;

  float2 stv[8];

  auto stage_load = [&](int t) {
    const int kbase = k0 + t * SK;
    #pragma unroll
    for (int j = 0; j < 8; ++j) {
      const int idx = j * 128 + tid;
      const int kp  = idx & 7;
      const int row = idx >> 3;
      const int kg  = kbase + kp * 2;
      float2 v; v.x = 0.f; v.y = 0.f;
      if (kg < kend) {
        const float* xp = x + (row0 + row) * DIN + kg;
        if (kg + 1 < kend) v = *(const float2*)xp;
        else v.x = *xp;
      }
      stv[j] = v;
    }
  };
  auto stage_write = [&](int bi) {
    #pragma unroll
    for (int j = 0; j < 8; ++j) {
      const int idx = j * 128 + tid;
      const int kp  = idx & 7;
      const int row = idx >> 3;
      xs[bi][kp * 2][row]     = stv[j].x;
      xs[bi][kp * 2 + 1][row] = stv[j].y;
    }
  };

  stage_load(0);
  stage_write(0);
  __syncthreads();

  for (int t = 0; t < NSUB; ++t) {
    const int bi = t & 1;
    if (t + 1 < NSUB) stage_load(t + 1);

    const int kbase = k0 + t * SK;
    const float* xr = xsrd + bi * (SK * 132);
    #pragma unroll 4
    for (int kk = 0; kk < SK; ++kk) {
      int kw = kbase + kk; kw = (kw < DIN) ? kw : (DIN - 1);
      const float4 x4 = *(const float4*)(xr + kk * 132);
      const float4 wv0 = *(const float4*)(wbase + kw * 32);
      const float4 wv1 = *(const float4*)(wbase + kw * 32 + 4);
      const float xv[4] = {x4.x, x4.y, x4.z, x4.w};
      const float wv[8] = {wv0.x, wv0.y, wv0.z, wv0.w, wv1.x, wv1.y, wv1.z, wv1.w};
      #pragma unroll
      for (int i = 0; i < 4; ++i)
        #pragma unroll
        for (int j = 0; j < 8; ++j)
          acc[i][j] += xv[i] * wv[j];
    }

    if (t + 1 < NSUB) stage_write((t + 1) & 1);
    __syncthreads();
  }

  float* ps = p + (long)s * (16384 * 32);
  #pragma unroll
  for (int i = 0; i < 4; ++i) {
    const long row = row0 + rg * 4 + i;
    float4 a; a.x = acc[i][0]; a.y = acc[i][1]; a.z = acc[i][2]; a.w = acc[i][3];
    float4 b; b.x = acc[i][4]; b.y = acc[i][5]; b.z = acc[i][6]; b.w = acc[i][7];
    *(float4*)(ps + row * 32 + h0)     = a;
    *(float4*)(ps + row * 32 + h0 + 4) = b;
  }
}

// ---------------- K2: h = sum_s p[s]+b1 (inline); em = relu(conv1d(h)+cb)@w2+b2 ----
__global__ __launch_bounds__(256) void k2_conv(
    const float* __restrict__ p, const float* __restrict__ b1,
    const float* __restrict__ cw, const float* __restrict__ cb,
    const float* __restrict__ w2, const float* __restrict__ b2,
    float* __restrict__ em) {
  const int g = blockIdx.x * 256 + threadIdx.x;   // 0..131071
  const int row  = g >> 3;
  const int isub = g & 7;
  const int i0   = isub << 2;
  const int li   = row & (LSEQ - 1);

  const float4* p4 = (const float4*)p;
  const float4 bv = ((const float4*)b1)[isub];
  float4 z; z.x = z.y = z.z = z.w = 0.f;

  auto hrow = [&](int r) -> float4 {
    float4 a = p4[(long)r * 8 + isub];
    #pragma unroll
    for (int s = 1; s < SPLITK; ++s) {
      float4 v = p4[(long)s * 131072 + (long)r * 8 + isub];
      a.x += v.x; a.y += v.y; a.z += v.z; a.w += v.w;
    }
    a.x += bv.x; a.y += bv.y; a.z += bv.z; a.w += bv.w;
    return a;
  };

  float4 hm = (li > 0)        ? hrow(row - 1) : z;
  float4 hc = hrow(row);
  float4 hp = (li < LSEQ - 1) ? hrow(row + 1) : z;

  float s[16];
  #pragma unroll
  for (int o = 0; o < 16; ++o) {
    const float4* wp = (const float4*)(cw + o * 96 + i0 * 3);
    const float4 wa = wp[0], wb = wp[1], wc = wp[2];
    s[o] = hm.x * wa.x + hc.x * wa.y + hp.x * wa.z
         + hm.y * wa.w + hc.y * wb.x + hp.y * wb.y
         + hm.z * wb.z + hc.z * wb.w + hp.z * wc.x
         + hm.w * wc.y + hc.w * wc.z + hp.w * wc.w;
  }
  #pragma unroll
  for (int o = 0; o < 16; ++o) {
    s[o] += __shfl_xor(s[o], 1, 8);
    s[o] += __shfl_xor(s[o], 2, 8);
    s[o] += __shfl_xor(s[o], 4, 8);
  }
  if (isub == 0) {
    float e0 = b2[0], e1 = b2[1];
    #pragma unroll
    for (int o = 0; o < 16; ++o) {
      float rr = fmaxf(s[o] + cb[o], 0.f);
      e0 += rr * w2[o * 2];
      e1 += rr * w2[o * 2 + 1];
    }
    float2 ev; ev.x = e0; ev.y = e1;
    *(float2*)(em + (long)row * 2) = ev;
  }
}

// ---------------- K3: per-batch CRF (score, log-partition, Viterbi) ----------------
__global__ __launch_bounds__(256) void k3_crf(
    const float* __restrict__ em, const int* __restrict__ tokens_length,
    const int* __restrict__ labels, const float* __restrict__ start_trans,
    const float* __restrict__ end_trans, const float* __restrict__ trans,
    float* __restrict__ llh, float* __restrict__ out) {
  __shared__ float sem[LSEQ * 2 + 64];     // pad for prefetch overrun
  __shared__ float2 vst[LSEQ];             // (v0,v1) trajectory
  __shared__ unsigned char hist[LSEQ];
  __shared__ float4 mats[256];
  __shared__ float red[256];
  __shared__ unsigned char bmA[256], bmB[256];
  __shared__ int s_last;

  const int t = threadIdx.x;
  const int b = blockIdx.x;
  const int len = tokens_length[b];
  const float t00 = trans[0], t01 = trans[1], t10 = trans[2], t11 = trans[3];
  const float st0 = start_trans[0], st1 = start_trans[1];
  const float en0 = end_trans[0], en1 = end_trans[1];
  const int* lab = labels + b * LSEQ;

  {
    const float4* src4 = (const float4*)(em + (long)b * LSEQ * 2);
    float4* dst4 = (float4*)sem;
    #pragma unroll
    for (int i = t; i < LSEQ * 2 / 4; i += 256) dst4[i] = src4[i];
    #pragma unroll
    for (int l = t; l < LSEQ; l += 256) hist[l] = 2;
    // zero the pad
    if (t < 16) ((float4*)(sem + LSEQ * 2))[t] = make_float4(0.f, 0.f, 0.f, 0.f);
  }
  __syncthreads();

  // ---- gold-score partial (parallel) ----
  float sc = 0.f;
  {
    const int base = t * 8;
    #pragma unroll
    for (int k = 0; k < 8; ++k) {
      int l = base + k;
      if (l >= 1 && l < len) {
        int lp = lab[l - 1], lc = lab[l];
        sc += trans[lp * 2 + lc] + sem[2 * l + lc];
      }
    }
  }
  red[t] = sc;

  // ---- log-partition chunk product (log-semiring 2x2) ----
  float p00 = 0.f, p01 = -1e30f, p10 = -1e30f, p11 = 0.f;
  {
    int lo = t * 8; if (lo < 1) lo = 1;
    int hi = t * 8 + 8; if (hi > len) hi = len;
    for (int l = lo; l < hi; ++l) {
      float e0 = sem[2 * l], e1 = sem[2 * l + 1];
      float n00 = lsef(p00 + t00, p01 + t10) + e0;
      float n01 = lsef(p00 + t01, p01 + t11) + e1;
      float n10 = lsef(p10 + t00, p11 + t10) + e0;
      float n11 = lsef(p10 + t01, p11 + t11) + e1;
      p00 = n00; p01 = n01; p10 = n10; p11 = n11;
    }
  }
  { float4 m; m.x = p00; m.y = p01; m.z = p10; m.w = p11; mats[t] = m; }
  __syncthreads();

  for (int n = 128; n >= 1; n >>= 1) {
    if (t < n) red[t] += red[t + n];
    __syncthreads();
  }
  for (int n = 128; n >= 1; n >>= 1) {
    float4 A, B; const bool act = (t < n);
    if (act) { A = mats[2 * t]; B = mats[2 * t + 1]; }
    __syncthreads();
    if (act) {
      float4 C;
      C.x = lsef(A.x + B.x, A.y + B.z);
      C.y = lsef(A.x + B.y, A.y + B.w);
      C.z = lsef(A.z + B.x, A.w + B.z);
      C.w = lsef(A.z + B.y, A.w + B.w);
      mats[t] = C;
    }
    __syncthreads();
  }

  if (t == 0) {
    int lab0 = lab[0];
    float s0 = (lab0 ? st1 : st0) + sem[lab0];
    int labe = lab[len - 1];
    float score = red[0] + s0 + (labe ? en1 : en0);
    float4 M = mats[0];
    float a00 = st0 + sem[0], a01 = st1 + sem[1];
    float af0 = lsef(a00 + M.x, a01 + M.z);
    float af1 = lsef(a00 + M.y, a01 + M.w);
    float norm = lsef(af0 + en0, af1 + en1);
    llh[b] = score - norm;
  }

  // ---- sequential Viterbi value chain (bit-exact ref order), prefetched ----
  if (t == 0) {
    float v0 = st0 + sem[0], v1 = st1 + sem[1];
    float2 vv; vv.x = v0; vv.y = v1;
    vst[0] = vv;
    float2 eb[VGRP];
    #pragma unroll
    for (int k = 0; k < VGRP; ++k) eb[k] = *(const float2*)(sem + 2 * (1 + k));
    int l0 = 1;
    for (; l0 + VGRP <= len; l0 += VGRP) {
      float2 ec[VGRP];
      #pragma unroll
      for (int k = 0; k < VGRP; ++k) ec[k] = eb[k];
      #pragma unroll
      for (int k = 0; k < VGRP; ++k)
        eb[k] = *(const float2*)(sem + 2 * (l0 + VGRP + k));
      #pragma unroll
      for (int k = 0; k < VGRP; ++k) {
        float s00 = v0 + t00, s10 = v1 + t10;
        float s01 = v0 + t01, s11 = v1 + t11;
        v0 = fmaxf(s00, s10) + ec[k].x;
        v1 = fmaxf(s01, s11) + ec[k].y;
        float2 w; w.x = v0; w.y = v1;
        vst[l0 + k] = w;
      }
    }
    for (int k = 0; l0 + k < len; ++k) {
      float s00 = v0 + t00, s10 = v1 + t10;
      float s01 = v0 + t01, s11 = v1 + t11;
      v0 = fmaxf(s00, s10) + eb[k].x;
      v1 = fmaxf(s01, s11) + eb[k].y;
      float2 w; w.x = v0; w.y = v1;
      vst[l0 + k] = w;
    }
    s_last = (v0 + en0 >= v1 + en1) ? 0 : 1;
  }
  __syncthreads();

  // ---- parallel decision recompute: h[l] from vst[l-1] (bit-exact) ----
  {
    int lo = (t == 0) ? 1 : t * 8;
    int hi = t * 8 + 8; if (hi > len) hi = len;
    for (int l = lo; l < hi; ++l) {
      float2 vp = vst[l - 1];
      float s00 = vp.x + t00, s10 = vp.y + t10;
      float s01 = vp.x + t01, s11 = vp.y + t11;
      hist[l] = (unsigned char)((s00 >= s10 ? 0 : 1) | ((s01 >= s11 ? 0 : 1) << 1));
    }
  }
  __syncthreads();
  const int last = s_last;

  // ---- backtrace: exact parallel map-composition suffix scan ----
  {
    int lo = (t == 0) ? 1 : t * 8;
    int hi = t * 8 + 8;
    int m0 = 0, m1 = 1;
    for (int l = hi - 1; l >= lo; --l) {
      int h = hist[l];
      m0 = (h >> m0) & 1;
      m1 = (h >> m1) & 1;
    }
    bmA[t] = (unsigned char)(m0 | (m1 << 1));
  }
  __syncthreads();
  {
    unsigned char* sarr = bmA; unsigned char* darr = bmB;
    for (int off = 1; off < 256; off <<= 1) {
      int a = sarr[t];
      int c = a;
      if (t + off < 256) {
        int bm = sarr[t + off];
        int c0 = (a >> (bm & 1)) & 1;
        int c1 = (a >> ((bm >> 1) & 1)) & 1;
        c = c0 | (c1 << 1);
      }
      darr[t] = (unsigned char)c;
      __syncthreads();
      unsigned char* tmp = sarr; sarr = darr; darr = tmp;
    }
    int xv = (t == 255) ? last : ((sarr[t + 1] >> last) & 1);
    int lo = (t == 0) ? 1 : t * 8;
    int hi = t * 8 + 8;
    float* tout = out + 1 + b * LSEQ;
    for (int l = hi - 1; l >= lo; --l) {
      xv = (hist[l] >> xv) & 1;
      int pidx = l - 1;
      tout[pidx] = (pidx < len) ? (float)xv : 0.0f;
    }
    if (t == 255) tout[LSEQ - 1] = ((LSEQ - 1) < len) ? (float)last : 0.0f;
  }
}

// ---------------- K4: deterministic final sum ----------------
__global__ void k4_final(const float* __restrict__ llh, float* __restrict__ out) {
  if (threadIdx.x == 0 && blockIdx.x == 0) {
    float s = 0.f;
    #pragma unroll
    for (int i = 0; i < NB; ++i) s += llh[i];
    out[0] = -s;
  }
}

extern "C" void kernel_launch(void* const* d_in, const int* in_sizes, int n_in,
                              void* d_out, int out_size, void* d_ws, size_t ws_size,
                              hipStream_t stream) {
  const float* x  = (const float*)d_in[0];
  const int*   tl = (const int*)d_in[1];
  const int*   lb = (const int*)d_in[2];
  const float* w1 = (const float*)d_in[3];
  const float* b1 = (const float*)d_in[4];
  const float* cw = (const float*)d_in[5];
  const float* cb = (const float*)d_in[6];
  const float* w2 = (const float*)d_in[7];
  const float* b2 = (const float*)d_in[8];
  const float* st = (const float*)d_in[9];
  const float* en = (const float*)d_in[10];
  const float* tr = (const float*)d_in[11];
  float* out = (float*)d_out;
  float* ws  = (float*)d_ws;

  float* p   = ws;                                 // 8 * 524288 floats (16 MB)
  float* em  = ws + (long)SPLITK * 524288;         // 32768 floats
  float* llh = em + 32768;                         // 8 floats

  hipLaunchKernelGGL(k1_gemm, dim3(128 * SPLITK), dim3(128), 0, stream, x, w1, p);
  hipLaunchKernelGGL(k2_conv, dim3(512), dim3(256), 0, stream, p, b1, cw, cb, w2, b2, em);
  hipLaunchKernelGGL(k3_crf, dim3(NB), dim3(256), 0, stream, em, tl, lb, st, en, tr, llh, out);
  hipLaunchKernelGGL(k4_final, dim3(1), dim3(64), 0, stream, llh, out);
}